// Round 1
// baseline (121.075 us; speedup 1.0000x reference)
//
#include <hip/hip_runtime.h>
#include <hip/hip_bf16.h>

typedef __bf16 bf16x8 __attribute__((ext_vector_type(8)));
typedef __bf16 bf16x4 __attribute__((ext_vector_type(4)));
typedef float f32x4 __attribute__((ext_vector_type(4)));

#define B_N 2048
#define O_N 2048
#define K_N 64

// ---------------------------------------------------------------------------
// prep: At[o][j][i] = (inv[o][i][j])^2 as bf16  (transposed so MFMA B-frags are
//       contiguous 16B ds_read_b128);  mT[o][i] = means[i][o] (f32, exact).
// ---------------------------------------------------------------------------
__global__ __launch_bounds__(256) void rbf_prep(
    const float* __restrict__ inv, const float* __restrict__ means,
    __bf16* __restrict__ At, float* __restrict__ mT)
{
    __shared__ float s[64 * 65];              // +1 pad: conflict-free transpose
    const int o = blockIdx.x;
    const int tid = threadIdx.x;
    const float4* src = (const float4*)(inv + (size_t)o * 4096);
#pragma unroll
    for (int k = 0; k < 4; ++k) {
        const int idx = k * 256 + tid;        // float4 index 0..1023
        const float4 v = src[idx];
        const int i = idx >> 4;               // source row
        const int j0 = (idx & 15) * 4;        // source col
        s[i * 65 + j0 + 0] = v.x * v.x;
        s[i * 65 + j0 + 1] = v.y * v.y;
        s[i * 65 + j0 + 2] = v.z * v.z;
        s[i * 65 + j0 + 3] = v.w * v.w;
    }
    if (tid < 64) mT[(size_t)o * 64 + tid] = means[(size_t)tid * O_N + o];
    __syncthreads();
#pragma unroll
    for (int k = 0; k < 4; ++k) {
        const int idx = k * 256 + tid;        // output bf16x4 index
        const int j = idx >> 4;               // output row (= source col)
        const int i0 = (idx & 15) * 4;        // output col (= source row)
        bf16x4 v;
        v[0] = (__bf16)s[(i0 + 0) * 65 + j];
        v[1] = (__bf16)s[(i0 + 1) * 65 + j];
        v[2] = (__bf16)s[(i0 + 2) * 65 + j];
        v[3] = (__bf16)s[(i0 + 3) * 65 + j];
        *(bf16x4*)(At + (size_t)o * 4096 + (size_t)idx * 4) = v;
    }
}

// 16-lane-group sum: xor1/xor2 via DPP quad_perm (VALU pipe), xor4/8 ds_swizzle
__device__ __forceinline__ float red16(float q)
{
    int t;
    t = __builtin_amdgcn_update_dpp(0, __float_as_int(q), 0xB1, 0xF, 0xF, true); // ^1
    q += __int_as_float(t);
    t = __builtin_amdgcn_update_dpp(0, __float_as_int(q), 0x4E, 0xF, 0xF, true); // ^2
    q += __int_as_float(t);
    q += __int_as_float(__builtin_amdgcn_ds_swizzle(__float_as_int(q), 0x101F)); // ^4
    q += __int_as_float(__builtin_amdgcn_ds_swizzle(__float_as_int(q), 0x201F)); // ^8
    return q;
}

// ---------------------------------------------------------------------------
// main: per block = 128 rows x 32 o's. 4 waves, each wave = 32 rows (2 chunks
// of 16). Per o: Y = (x - m_o) @ A_o via 16x16x32 bf16 MFMA (d bf16 only on
// the MFMA side), then q = Y . d with d rebuilt in exact f32 (halves rounding
// error), out = exp(-q/2). At double-buffered in LDS with XOR swizzle.
// ---------------------------------------------------------------------------
__global__ __launch_bounds__(256) void rbf_main(
    const float* __restrict__ x, const __bf16* __restrict__ At,
    const float* __restrict__ mT, float* __restrict__ out)
{
    __shared__ __align__(16) __bf16 sAt[2][4096];
    __shared__ __align__(16) float sM[2][64];

    const int tid = threadIdx.x;
    const int wave = tid >> 6;
    const int lane = tid & 63;
    const int g = lane >> 4;   // 0..3: k-group / acc row-group
    const int c = lane & 15;   // 0..15: A-frag row / acc col

    // 1024 blocks = 8 XCD x (8 ogroups x 16 bgroups): each XCD reuses a 2MB At
    // slice from its private L2.
    const int wg = (int)blockIdx.x;
    const int xcd = wg & 7;
    const int loc = wg >> 3;               // 0..127
    const int og = xcd * 8 + (loc >> 4);   // 0..63
    const int bg = loc & 15;               // 0..15
    const int oBase = og * 32;
    const int rowW = bg * 128 + wave * 32;

    // x in MFMA A-fragment layout: lane holds x[rowW+cc*16+c][h*32+g*8 + 0..7]
    float xf[2][2][8];
#pragma unroll
    for (int cc = 0; cc < 2; ++cc) {
        const int row = rowW + cc * 16 + c;
#pragma unroll
        for (int h = 0; h < 2; ++h) {
            const float4* p = (const float4*)(x + (size_t)row * 64 + h * 32 + g * 8);
            const float4 a = p[0], b = p[1];
            xf[cc][h][0] = a.x; xf[cc][h][1] = a.y; xf[cc][h][2] = a.z; xf[cc][h][3] = a.w;
            xf[cc][h][4] = b.x; xf[cc][h][5] = b.y; xf[cc][h][6] = b.z; xf[cc][h][7] = b.w;
        }
    }
    // x in accumulator (row-dot) layout: lane holds x[rowW+cc*16+4g+p][16t+c]
    float xr[2][4][4];
#pragma unroll
    for (int cc = 0; cc < 2; ++cc)
#pragma unroll
        for (int p = 0; p < 4; ++p) {
            const int row = rowW + cc * 16 + g * 4 + p;
#pragma unroll
            for (int t = 0; t < 4; ++t)
                xr[cc][p][t] = x[(size_t)row * 64 + t * 16 + c];
        }

    bf16x8 st0, st1;
    float mreg = 0.f;

    // prologue: stage o = oBase into buffer 0 (XOR swizzle on LDS write side)
    {
        const bf16x8* gs = (const bf16x8*)(At + (size_t)oBase * 4096);
        st0 = gs[tid]; st1 = gs[256 + tid];
        if (tid < 64) mreg = mT[(size_t)oBase * 64 + tid];
        const int L0 = tid * 16, L1 = 4096 + tid * 16;
        *(bf16x8*)((char*)&sAt[0][0] + (L0 ^ (((L0 >> 7) & 7) << 4))) = st0;
        *(bf16x8*)((char*)&sAt[0][0] + (L1 ^ (((L1 >> 7) & 7) << 4))) = st1;
        if (tid < 64) sM[0][tid] = mreg;
    }

    float qbuf[2][4];
    qbuf[0][0]=qbuf[0][1]=qbuf[0][2]=qbuf[0][3]=0.f;
    qbuf[1][0]=qbuf[1][1]=qbuf[1][2]=qbuf[1][3]=0.f;

#pragma unroll 1
    for (int i = 0; i < 32; ++i) {
        __syncthreads();
        if (i < 31) {  // issue next-o global loads early; latency hides under compute
            const bf16x8* gs = (const bf16x8*)(At + (size_t)(oBase + i + 1) * 4096);
            st0 = gs[tid]; st1 = gs[256 + tid];
            if (tid < 64) mreg = mT[(size_t)(oBase + i + 1) * 64 + tid];
        }
        const int buf = i & 1;

        // B fragments: B[k=i][n=j], lane: n = 16t + c, k = h*32 + g*8 + e
        bf16x8 bfr[4][2];
#pragma unroll
        for (int t = 0; t < 4; ++t)
#pragma unroll
            for (int h = 0; h < 2; ++h) {
                const int j = t * 16 + c;
                const int L = j * 128 + h * 64 + g * 16;
                bfr[t][h] = *(const bf16x8*)((const char*)&sAt[buf][0] + (L ^ ((j & 7) << 4)));
            }
        // means in frag layout (broadcast reads) and in row-dot layout
        float mf[2][8];
#pragma unroll
        for (int h = 0; h < 2; ++h) {
            const float4* mp = (const float4*)&sM[buf][h * 32 + g * 8];
            const float4 a = mp[0], b = mp[1];
            mf[h][0]=a.x; mf[h][1]=a.y; mf[h][2]=a.z; mf[h][3]=a.w;
            mf[h][4]=b.x; mf[h][5]=b.y; mf[h][6]=b.z; mf[h][7]=b.w;
        }
        float lm[4];
#pragma unroll
        for (int t = 0; t < 4; ++t) lm[t] = sM[buf][t * 16 + c];

#pragma unroll
        for (int cc = 0; cc < 2; ++cc) {
            // d = x - m in f32, rounded to bf16 only for the MFMA operand
            bf16x8 a0, a1;
#pragma unroll
            for (int e = 0; e < 8; ++e) {
                a0[e] = (__bf16)(xf[cc][0][e] - mf[0][e]);
                a1[e] = (__bf16)(xf[cc][1][e] - mf[1][e]);
            }
            f32x4 acc[4];
#pragma unroll
            for (int t = 0; t < 4; ++t) {
                f32x4 z = {0.f, 0.f, 0.f, 0.f};
                acc[t] = __builtin_amdgcn_mfma_f32_16x16x32_bf16(a0, bfr[t][0], z, 0, 0, 0);
                acc[t] = __builtin_amdgcn_mfma_f32_16x16x32_bf16(a1, bfr[t][1], acc[t], 0, 0, 0);
            }
            // row-dot q = sum_j Y[r][j] * d[r][j], d exact f32; reduce over 16 c-lanes
#pragma unroll
            for (int p = 0; p < 4; ++p) {
                float q = 0.f;
#pragma unroll
                for (int t = 0; t < 4; ++t)
                    q = fmaf(acc[t][p], xr[cc][p][t] - lm[t], q);
                q = red16(q);
                const float ev = exp2f(q * -0.72134752044448170368f); // exp(-q/2)
                if ((i & 15) == c) qbuf[cc][p] = ev;   // lane c owns o = ob + c
            }
        }
        if ((i & 15) == 15) {   // coalesced store of 16 o's per row
            const int ob = oBase + (i & ~15);
#pragma unroll
            for (int cc = 0; cc < 2; ++cc)
#pragma unroll
                for (int p = 0; p < 4; ++p) {
                    const int row = rowW + cc * 16 + g * 4 + p;
                    out[(size_t)row * O_N + ob + c] = qbuf[cc][p];
                }
        }
        if (i < 31) {  // write staged regs into the other buffer (swizzled)
            const int nb = (i + 1) & 1;
            const int L0 = tid * 16, L1 = 4096 + tid * 16;
            *(bf16x8*)((char*)&sAt[nb][0] + (L0 ^ (((L0 >> 7) & 7) << 4))) = st0;
            *(bf16x8*)((char*)&sAt[nb][0] + (L1 ^ (((L1 >> 7) & 7) << 4))) = st1;
            if (tid < 64) sM[nb][tid] = mreg;
        }
    }
}

extern "C" void kernel_launch(void* const* d_in, const int* in_sizes, int n_in,
                              void* d_out, int out_size, void* d_ws, size_t ws_size,
                              hipStream_t stream)
{
    const float* x = (const float*)d_in[0];
    const float* means = (const float*)d_in[1];
    const float* inv = (const float*)d_in[2];
    float* out = (float*)d_out;

    // workspace: At (bf16, 16.78 MB) then mT (f32, 0.5 MB)
    __bf16* At = (__bf16*)d_ws;
    float* mT = (float*)((char*)d_ws + (size_t)O_N * K_N * K_N * sizeof(__bf16));

    rbf_prep<<<dim3(O_N), dim3(256), 0, stream>>>(inv, means, At, mT);
    rbf_main<<<dim3(1024), dim3(256), 0, stream>>>(x, At, mT, out);

    (void)in_sizes; (void)n_in; (void)out_size; (void)ws_size;
}

// Round 2
// 70.072 us; speedup vs baseline: 1.7279x; 1.7279x over previous
//
#include <hip/hip_runtime.h>
#include <hip/hip_bf16.h>

typedef __bf16 bf16x8 __attribute__((ext_vector_type(8)));
typedef float f32x4 __attribute__((ext_vector_type(4)));
typedef float f32x16 __attribute__((ext_vector_type(16)));
typedef int i32x4 __attribute__((ext_vector_type(4)));

#define B_N 2048
#define O_N 2048
#define K_N 64

// ---------------------------------------------------------------------------
// prep: per o, build
//   Atp[o][s][j][kl] = bf16( inv[o][16s+kl][j]^2 )   (s=0..3, j=0..63, kl=0..15)
//   cPack[o][j] = (hi,lo) bf16 pair of  -(u_j + w_j),  u = A^T m, w = A m
//   kArr[o]    = m^T A m   (f32)
// so that  d^T A d = sum_j (sum_i Aop[j][i] x_i - (u_j+w_j)) * x_j + k
// ---------------------------------------------------------------------------
__global__ __launch_bounds__(256) void rbf_prep(
    const float* __restrict__ inv, const float* __restrict__ means,
    __bf16* __restrict__ Atp, unsigned int* __restrict__ cPack,
    float* __restrict__ kArr)
{
    __shared__ float s[64 * 65];     // s[i*65+j] = inv[o][i][j]^2, +1 pad
    __shared__ float mld[64];
    __shared__ float uw[128];
    const int o = blockIdx.x;
    const int t = threadIdx.x;
    const float4* src = (const float4*)(inv + (size_t)o * 4096);
#pragma unroll
    for (int k = 0; k < 4; ++k) {
        const int idx = k * 256 + t;
        const float4 v = src[idx];
        const int i = idx >> 4;
        const int j0 = (idx & 15) * 4;
        s[i * 65 + j0 + 0] = v.x * v.x;
        s[i * 65 + j0 + 1] = v.y * v.y;
        s[i * 65 + j0 + 2] = v.z * v.z;
        s[i * 65 + j0 + 3] = v.w * v.w;
    }
    if (t < 64) mld[t] = means[(size_t)t * O_N + o];
    __syncthreads();
    if (t < 64) {                 // u_j = sum_i A[i][j] m_i
        float u = 0.f;
#pragma unroll
        for (int i = 0; i < 64; ++i) u = fmaf(s[i * 65 + t], mld[i], u);
        uw[t] = u;
    } else if (t < 128) {         // w_j = sum_i A[j][i] m_i
        const int j = t - 64;
        float w = 0.f;
#pragma unroll
        for (int i = 0; i < 64; ++i) w = fmaf(s[j * 65 + i], mld[i], w);
        uw[64 + j] = w;
    }
    __syncthreads();
    if (t < 64) {
        const float c = -(uw[t] + uw[64 + t]);
        const __bf16 hi = (__bf16)c;
        const __bf16 lo = (__bf16)(c - (float)hi);
        const unsigned int hb = __builtin_bit_cast(unsigned short, hi);
        const unsigned int lb = __builtin_bit_cast(unsigned short, lo);
        cPack[(size_t)o * 64 + t] = hb | (lb << 16);
    }
    if (t == 0) {
        float kk = 0.f;
#pragma unroll
        for (int j = 0; j < 64; ++j) kk = fmaf(uw[j], mld[j], kk);
        kArr[o] = kk;
    }
#pragma unroll
    for (int r = 0; r < 2; ++r) {
        const int ch = r * 256 + t;
        const int ss = ch >> 7;
        const int j = (ch >> 1) & 63;
        const int h = ch & 1;
        bf16x8 v;
#pragma unroll
        for (int e = 0; e < 8; ++e)
            v[e] = (__bf16)s[(16 * ss + 8 * h + e) * 65 + j];
        *(bf16x8*)(Atp + (size_t)o * 4096 + (size_t)ch * 8) = v;
    }
}

// ---------------------------------------------------------------------------
// main: block = 128 rows x 32 o's, 4 waves x 32 rows.
// C-layout (32x32): lane&31 = col b; rows j = (reg&3)+8*(reg>>2)+4*(lane>>5).
// ---------------------------------------------------------------------------
__global__ __launch_bounds__(256, 3) void rbf_main(
    const float* __restrict__ x, const __bf16* __restrict__ Atp,
    const unsigned int* __restrict__ cPack, const float* __restrict__ kArr,
    float* __restrict__ out)
{
    __shared__ __align__(16) __bf16 sA[2][4096];

    const int tid = threadIdx.x;
    const int wave = tid >> 6;
    const int lane = tid & 63;
    const int b = lane & 31;
    const int h = lane >> 5;

    const int wg = (int)blockIdx.x;
    const int xcd = wg & 7;
    const int loc = wg >> 3;
    const int og = xcd * 8 + (loc >> 4);
    const int bg = loc & 15;
    const int oBase = og * 32;
    const int rowW = bg * 128 + wave * 32;
    const int row = rowW + b;
    const float* xr = x + (size_t)row * K_N;

    // B-op fragments (bf16 x): lane holds x[row][16s + 8h + e]
    bf16x8 xb[4];
#pragma unroll
    for (int ss = 0; ss < 4; ++ss) {
        const float4 a = *(const float4*)(xr + ss * 16 + h * 8);
        const float4 bb = *(const float4*)(xr + ss * 16 + h * 8 + 4);
        bf16x8 v;
        v[0] = (__bf16)a.x;  v[1] = (__bf16)a.y;
        v[2] = (__bf16)a.z;  v[3] = (__bf16)a.w;
        v[4] = (__bf16)bb.x; v[5] = (__bf16)bb.y;
        v[6] = (__bf16)bb.z; v[7] = (__bf16)bb.w;
        xb[ss] = v;
    }
    // dot-layout x (f32): xd[mt][rq][e] = x[row][mt*32 + 8*rq + 4*h + e]
    f32x4 xd[2][4];
#pragma unroll
    for (int mt = 0; mt < 2; ++mt)
#pragma unroll
        for (int rq = 0; rq < 4; ++rq)
            xd[mt][rq] = *(const f32x4*)(xr + mt * 32 + rq * 8 + h * 4);

    const i32x4 onesI = { h ? 0 : 0x3F803F80, 0, 0, 0 };
    const bf16x8 onesF = __builtin_bit_cast(bf16x8, onesI);
    const f32x16 zz = {0.f,0.f,0.f,0.f,0.f,0.f,0.f,0.f,
                       0.f,0.f,0.f,0.f,0.f,0.f,0.f,0.f};

    const bf16x8* gA = (const bf16x8*)Atp;
    bf16x8 st0, st1;
    st0 = gA[(size_t)oBase * 512 + tid];
    st1 = gA[(size_t)oBase * 512 + 256 + tid];
    ((bf16x8*)sA[0])[tid] = st0;
    ((bf16x8*)sA[0])[256 + tid] = st1;

    float q4[4];

#pragma unroll 4
    for (int i = 0; i < 32; ++i) {
        __syncthreads();
        if (i < 31) {
            const size_t gbase = (size_t)(oBase + i + 1) * 512;
            st0 = gA[gbase + tid];
            st1 = gA[gbase + 256 + tid];
        }
        const __bf16* bufp = sA[i & 1];

        const unsigned int cw0 = cPack[(size_t)(oBase + i) * 64 + b];
        const unsigned int cw1 = cPack[(size_t)(oBase + i) * 64 + 32 + b];
        const float kk = kArr[oBase + i];
        const i32x4 c0i = { h ? 0 : (int)cw0, 0, 0, 0 };
        const i32x4 c1i = { h ? 0 : (int)cw1, 0, 0, 0 };
        const bf16x8 cf0 = __builtin_bit_cast(bf16x8, c0i);
        const bf16x8 cf1 = __builtin_bit_cast(bf16x8, c1i);

        f32x16 acc0 = zz, acc1 = zz;
#pragma unroll
        for (int ss = 0; ss < 4; ++ss) {
            const bf16x8 af0 = *(const bf16x8*)(bufp + ss * 1024 + b * 16 + h * 8);
            acc0 = __builtin_amdgcn_mfma_f32_32x32x16_bf16(af0, xb[ss], acc0, 0, 0, 0);
        }
#pragma unroll
        for (int ss = 0; ss < 4; ++ss) {
            const bf16x8 af1 = *(const bf16x8*)(bufp + ss * 1024 + (32 + b) * 16 + h * 8);
            acc1 = __builtin_amdgcn_mfma_f32_32x32x16_bf16(af1, xb[ss], acc1, 0, 0, 0);
        }
        acc0 = __builtin_amdgcn_mfma_f32_32x32x16_bf16(cf0, onesF, acc0, 0, 0, 0);
        acc1 = __builtin_amdgcn_mfma_f32_32x32x16_bf16(cf1, onesF, acc1, 0, 0, 0);

        float q = 0.f;
#pragma unroll
        for (int rg = 0; rg < 4; ++rg)
#pragma unroll
            for (int e = 0; e < 4; ++e)
                q = fmaf(acc0[rg * 4 + e], xd[0][rg][e], q);
#pragma unroll
        for (int rg = 0; rg < 4; ++rg)
#pragma unroll
            for (int e = 0; e < 4; ++e)
                q = fmaf(acc1[rg * 4 + e], xd[1][rg][e], q);
        q += __shfl_xor(q, 32, 64);
        const float ev = exp2f((q + kk) * -0.72134752044448170368f);
        q4[i & 3] = ev;

        if ((i & 3) == 3 && h == 0) {
            const f32x4 v = {q4[0], q4[1], q4[2], q4[3]};
            *(f32x4*)(out + (size_t)row * O_N + oBase + (i - 3)) = v;
        }
        if (i < 31) {
            ((bf16x8*)sA[(i + 1) & 1])[tid] = st0;
            ((bf16x8*)sA[(i + 1) & 1])[256 + tid] = st1;
        }
    }
}

extern "C" void kernel_launch(void* const* d_in, const int* in_sizes, int n_in,
                              void* d_out, int out_size, void* d_ws, size_t ws_size,
                              hipStream_t stream)
{
    const float* x = (const float*)d_in[0];
    const float* means = (const float*)d_in[1];
    const float* inv = (const float*)d_in[2];
    float* out = (float*)d_out;

    __bf16* Atp = (__bf16*)d_ws;                                  // 16.78 MB
    unsigned int* cPack = (unsigned int*)((char*)d_ws + (size_t)O_N * 4096 * sizeof(__bf16));
    float* kArr = (float*)((char*)cPack + (size_t)O_N * 64 * sizeof(unsigned int));

    rbf_prep<<<dim3(O_N), dim3(256), 0, stream>>>(inv, means, Atp, cPack, kArr);
    rbf_main<<<dim3(1024), dim3(256), 0, stream>>>(x, Atp, cPack, kArr, out);

    (void)in_sizes; (void)n_in; (void)out_size; (void)ws_size;
}

// Round 3
// 64.539 us; speedup vs baseline: 1.8760x; 1.0857x over previous
//
#include <hip/hip_runtime.h>
#include <hip/hip_bf16.h>

typedef __bf16 bf16x8 __attribute__((ext_vector_type(8)));
typedef float f32x4 __attribute__((ext_vector_type(4)));
typedef float f32x16 __attribute__((ext_vector_type(16)));

#define B_N 2048
#define O_N 2048
#define K_N 64

__device__ __forceinline__ void gld16(const void* g, void* l) {
    __builtin_amdgcn_global_load_lds(
        (const __attribute__((address_space(1))) void*)g,
        (__attribute__((address_space(3))) void*)l,
        16, 0, 0);
}

// ---------------------------------------------------------------------------
// prep outputs:
//   Atp[o]: A-op panel, element(ss,j,h,e) at ss*1024 + j*16 + h*8 + e
//           = bf16( inv[o][16ss+8h+e][j]^2 )          (8KB per o)
//   cPhi/cPlo[oblk]: c = -(A^T+A)m in bf16 hi/lo, MFMA-A-frag layout:
//           element = oblk*2048 + (j>>4)*512 + (o&31)*16 + (j&15)
//   kArr[o] = m^T A m (f32)
// ---------------------------------------------------------------------------
__global__ __launch_bounds__(256) void rbf_prep(
    const float* __restrict__ inv, const float* __restrict__ means,
    __bf16* __restrict__ Atp, __bf16* __restrict__ cPhi,
    __bf16* __restrict__ cPlo, float* __restrict__ kArr)
{
    __shared__ float s[64 * 65];     // s[i*65+j] = inv[o][i][j]^2, +1 pad
    __shared__ float mld[64];
    __shared__ float uw[128];
    const int o = blockIdx.x;
    const int t = threadIdx.x;
    const float4* src = (const float4*)(inv + (size_t)o * 4096);
#pragma unroll
    for (int k = 0; k < 4; ++k) {
        const int idx = k * 256 + t;
        const float4 v = src[idx];
        const int i = idx >> 4;
        const int j0 = (idx & 15) * 4;
        s[i * 65 + j0 + 0] = v.x * v.x;
        s[i * 65 + j0 + 1] = v.y * v.y;
        s[i * 65 + j0 + 2] = v.z * v.z;
        s[i * 65 + j0 + 3] = v.w * v.w;
    }
    if (t < 64) mld[t] = means[(size_t)t * O_N + o];
    __syncthreads();
    if (t < 64) {                 // u_j = sum_i A[i][j] m_i
        float u = 0.f;
#pragma unroll
        for (int i = 0; i < 64; ++i) u = fmaf(s[i * 65 + t], mld[i], u);
        uw[t] = u;
    } else if (t < 128) {         // w_j = sum_i A[j][i] m_i
        const int j = t - 64;
        float w = 0.f;
#pragma unroll
        for (int i = 0; i < 64; ++i) w = fmaf(s[j * 65 + i], mld[i], w);
        uw[64 + j] = w;
    }
    __syncthreads();
    if (t < 64) {
        const float c = -(uw[t] + uw[64 + t]);
        const __bf16 hi = (__bf16)c;
        const __bf16 lo = (__bf16)(c - (float)hi);
        const size_t eidx = (size_t)(o >> 5) * 2048 + (size_t)(t >> 4) * 512
                          + (size_t)(o & 31) * 16 + (t & 15);
        cPhi[eidx] = hi;
        cPlo[eidx] = lo;
    }
    if (t == 0) {
        float kk = 0.f;
#pragma unroll
        for (int j = 0; j < 64; ++j) kk = fmaf(uw[j], mld[j], kk);
        kArr[o] = kk;
    }
#pragma unroll
    for (int r = 0; r < 2; ++r) {
        const int ch = r * 256 + t;
        const int ss = ch >> 7;
        const int j = (ch >> 1) & 63;
        const int h = ch & 1;
        bf16x8 v;
#pragma unroll
        for (int e = 0; e < 8; ++e)
            v[e] = (__bf16)s[(16 * ss + 8 * h + e) * 65 + j];
        *(bf16x8*)(Atp + (size_t)o * 4096 + (size_t)ch * 8) = v;
    }
}

// ---------------------------------------------------------------------------
// main: block = 128 rows x 32 o's, 4 waves x 32 rows.
//  - A-panel staged via global_load_lds (linear LDS dest, pre-swizzled global
//    src): LDS[L] = panel[swz(L)], swz(L) = L ^ (((L>>7)&7)<<4) (involution).
//    Reads at swz(R) are conflict-free (8 distinct bank-quads per 8 lanes).
//  - linear term: one 32o x 32b K=64 GEMM per block-wave (c hi/lo x x hi/lo),
//    scattered to sLin; per-o cost = 1 broadcast ds_read + 1 add.
// C-layout (32x32): col = lane&31, row = (reg&3)+8*(reg>>2)+4*(lane>>5).
// ---------------------------------------------------------------------------
__global__ __launch_bounds__(256, 4) void rbf_main(
    const float* __restrict__ x, const __bf16* __restrict__ Atp,
    const __bf16* __restrict__ cPhi, const __bf16* __restrict__ cPlo,
    const float* __restrict__ kArr, float* __restrict__ out)
{
    __shared__ __align__(16) __bf16 sA[2][4096];
    __shared__ __align__(16) float sLin[4][32][32];
    __shared__ float sK[32];

    const int tid = threadIdx.x;
    const int wave = tid >> 6;
    const int lane = tid & 63;
    const int b = lane & 31;
    const int h = lane >> 5;

    const int wg = (int)blockIdx.x;
    const int xcd = wg & 7;
    const int loc = wg >> 3;
    const int og = xcd * 8 + (loc >> 4);   // 0..63 (o-block), per-XCD L2 slice
    const int bg = loc & 15;
    const int oBase = og * 32;
    const int rowW = bg * 128 + wave * 32;
    const int row = rowW + b;
    const float* xr = x + (size_t)row * K_N;

    const f32x16 zz = {0.f,0.f,0.f,0.f,0.f,0.f,0.f,0.f,
                       0.f,0.f,0.f,0.f,0.f,0.f,0.f,0.f};

    // x fragments: hi bf16 (MFMA B-op), lo residual (lin GEMM only), f32 (dot)
    bf16x8 xh[4], xl[4];
#pragma unroll
    for (int ss = 0; ss < 4; ++ss) {
        const float* p = xr + ss * 16 + h * 8;
        bf16x8 vh, vl;
#pragma unroll
        for (int e = 0; e < 8; ++e) {
            const float v = p[e];
            const __bf16 hi = (__bf16)v;
            vh[e] = hi;
            vl[e] = (__bf16)(v - (float)hi);
        }
        xh[ss] = vh; xl[ss] = vl;
    }
    f32x4 xd[2][4];
#pragma unroll
    for (int mt = 0; mt < 2; ++mt)
#pragma unroll
        for (int rq = 0; rq < 4; ++rq)
            xd[mt][rq] = *(const f32x4*)(xr + mt * 32 + rq * 8 + h * 4);

    // ---- linear-term GEMM: lin[o][b] = sum_j c[o][j] * x[b][j] ----
    {
        const __bf16* ch = cPhi + (size_t)og * 2048;
        const __bf16* cl = cPlo + (size_t)og * 2048;
        f32x16 lin = zz;
#pragma unroll
        for (int ss = 0; ss < 4; ++ss) {
            const bf16x8 fh = *(const bf16x8*)(ch + ss * 512 + b * 16 + h * 8);
            const bf16x8 fl = *(const bf16x8*)(cl + ss * 512 + b * 16 + h * 8);
            lin = __builtin_amdgcn_mfma_f32_32x32x16_bf16(fh, xh[ss], lin, 0, 0, 0);
            lin = __builtin_amdgcn_mfma_f32_32x32x16_bf16(fh, xl[ss], lin, 0, 0, 0);
            lin = __builtin_amdgcn_mfma_f32_32x32x16_bf16(fl, xh[ss], lin, 0, 0, 0);
        }
#pragma unroll
        for (int r = 0; r < 16; ++r)
            sLin[wave][(r & 3) + 8 * (r >> 2) + 4 * h][b] = lin[r];
    }
    if (tid < 32) sK[tid] = kArr[oBase + tid];

    // ---- staging setup: linear LDS dest, swizzled global src ----
    const int L0 = tid * 16;
    const int L1 = 4096 + tid * 16;
    const int S0 = L0 ^ (((L0 >> 7) & 7) << 4);
    const int S1 = L1 ^ (((L1 >> 7) & 7) << 4);
    const char* gp = (const char*)(Atp + (size_t)oBase * 4096);
    gld16(gp + S0, (char*)&sA[0][0] + L0);
    gld16(gp + S1, (char*)&sA[0][0] + L1);

    // swizzled read offset for j=b (j=b+32 is +1024: same XOR bits)
    const int off0 = (b * 32 + h * 16) ^ (((b >> 2) & 7) << 4);

    float q4[4];
#pragma unroll 4
    for (int i = 0; i < 32; ++i) {
        __syncthreads();
        if (i < 31) {
            const char* gn = gp + (size_t)(i + 1) * 8192;
            char* ld = (char*)&sA[(i + 1) & 1][0];
            gld16(gn + S0, ld + L0);
            gld16(gn + S1, ld + L1);
        }
        const char* bufp = (const char*)&sA[i & 1][0];

        f32x16 acc0 = zz, acc1 = zz;
#pragma unroll
        for (int ss = 0; ss < 4; ++ss) {
            const bf16x8 a0 = *(const bf16x8*)(bufp + ss * 2048 + off0);
            acc0 = __builtin_amdgcn_mfma_f32_32x32x16_bf16(a0, xh[ss], acc0, 0, 0, 0);
        }
#pragma unroll
        for (int ss = 0; ss < 4; ++ss) {
            const bf16x8 a1 = *(const bf16x8*)(bufp + ss * 2048 + 1024 + off0);
            acc1 = __builtin_amdgcn_mfma_f32_32x32x16_bf16(a1, xh[ss], acc1, 0, 0, 0);
        }

        // dot (4 partial chains), then h-halves combine, then +lin +k, exp
        float p[4] = {0.f, 0.f, 0.f, 0.f};
#pragma unroll
        for (int rg = 0; rg < 4; ++rg)
#pragma unroll
            for (int e = 0; e < 4; ++e)
                p[rg] = fmaf(acc0[rg * 4 + e], xd[0][rg][e], p[rg]);
#pragma unroll
        for (int rg = 0; rg < 4; ++rg)
#pragma unroll
            for (int e = 0; e < 4; ++e)
                p[rg] = fmaf(acc1[rg * 4 + e], xd[1][rg][e], p[rg]);
        float q = (p[0] + p[1]) + (p[2] + p[3]);
        q += __shfl_xor(q, 32, 64);
        q += sLin[wave][i][b];
        const float ev = exp2f((q + sK[i]) * -0.72134752044448170368f);
        q4[i & 3] = ev;

        if ((i & 3) == 3 && h == 0) {
            const f32x4 v = {q4[0], q4[1], q4[2], q4[3]};
            *(f32x4*)(out + (size_t)row * O_N + oBase + (i - 3)) = v;
        }
    }
}

extern "C" void kernel_launch(void* const* d_in, const int* in_sizes, int n_in,
                              void* d_out, int out_size, void* d_ws, size_t ws_size,
                              hipStream_t stream)
{
    const float* x = (const float*)d_in[0];
    const float* means = (const float*)d_in[1];
    const float* inv = (const float*)d_in[2];
    float* out = (float*)d_out;

    char* w = (char*)d_ws;
    __bf16* Atp  = (__bf16*)w;                         // 16.78 MB
    __bf16* cPhi = (__bf16*)(w + (size_t)O_N * 4096 * 2);          // 256 KB
    __bf16* cPlo = (__bf16*)(w + (size_t)O_N * 4096 * 2 + 262144); // 256 KB
    float*  kArr = (float*)(w + (size_t)O_N * 4096 * 2 + 524288);  // 8 KB

    rbf_prep<<<dim3(O_N), dim3(256), 0, stream>>>(inv, means, Atp, cPhi, cPlo, kArr);
    rbf_main<<<dim3(1024), dim3(256), 0, stream>>>(x, Atp, cPhi, cPlo, kArr, out);

    (void)in_sizes; (void)n_in; (void)out_size; (void)ws_size;
}

// Round 4
// 64.073 us; speedup vs baseline: 1.8896x; 1.0073x over previous
//
#include <hip/hip_runtime.h>
#include <hip/hip_bf16.h>

typedef __bf16 bf16x8 __attribute__((ext_vector_type(8)));
typedef float f32x4 __attribute__((ext_vector_type(4)));
typedef float f32x16 __attribute__((ext_vector_type(16)));

#define B_N 2048
#define O_N 2048
#define K_N 64

__device__ __forceinline__ void gld16(const void* g, void* l) {
    __builtin_amdgcn_global_load_lds(
        (const __attribute__((address_space(1))) void*)g,
        (__attribute__((address_space(3))) void*)l,
        16, 0, 0);
}

// ---------------------------------------------------------------------------
// prep (unchanged from R3):
//   Atp[o]: A-op panel, element(ss,j,h,e) at ss*1024 + j*16 + h*8 + e
//           = bf16( inv[o][16ss+8h+e][j]^2 )          (8KB per o)
//   cPhi/cPlo: c = -(A^T+A)m in bf16 hi/lo, MFMA-A-frag layout
//   kArr[o] = m^T A m (f32)
// ---------------------------------------------------------------------------
__global__ __launch_bounds__(256) void rbf_prep(
    const float* __restrict__ inv, const float* __restrict__ means,
    __bf16* __restrict__ Atp, __bf16* __restrict__ cPhi,
    __bf16* __restrict__ cPlo, float* __restrict__ kArr)
{
    __shared__ float s[64 * 65];
    __shared__ float mld[64];
    __shared__ float uw[128];
    const int o = blockIdx.x;
    const int t = threadIdx.x;
    const float4* src = (const float4*)(inv + (size_t)o * 4096);
#pragma unroll
    for (int k = 0; k < 4; ++k) {
        const int idx = k * 256 + t;
        const float4 v = src[idx];
        const int i = idx >> 4;
        const int j0 = (idx & 15) * 4;
        s[i * 65 + j0 + 0] = v.x * v.x;
        s[i * 65 + j0 + 1] = v.y * v.y;
        s[i * 65 + j0 + 2] = v.z * v.z;
        s[i * 65 + j0 + 3] = v.w * v.w;
    }
    if (t < 64) mld[t] = means[(size_t)t * O_N + o];
    __syncthreads();
    if (t < 64) {
        float u = 0.f;
#pragma unroll
        for (int i = 0; i < 64; ++i) u = fmaf(s[i * 65 + t], mld[i], u);
        uw[t] = u;
    } else if (t < 128) {
        const int j = t - 64;
        float w = 0.f;
#pragma unroll
        for (int i = 0; i < 64; ++i) w = fmaf(s[j * 65 + i], mld[i], w);
        uw[64 + j] = w;
    }
    __syncthreads();
    if (t < 64) {
        const float c = -(uw[t] + uw[64 + t]);
        const __bf16 hi = (__bf16)c;
        const __bf16 lo = (__bf16)(c - (float)hi);
        const size_t eidx = (size_t)(o >> 5) * 2048 + (size_t)(t >> 4) * 512
                          + (size_t)(o & 31) * 16 + (t & 15);
        cPhi[eidx] = hi;
        cPlo[eidx] = lo;
    }
    if (t == 0) {
        float kk = 0.f;
#pragma unroll
        for (int j = 0; j < 64; ++j) kk = fmaf(uw[j], mld[j], kk);
        kArr[o] = kk;
    }
#pragma unroll
    for (int r = 0; r < 2; ++r) {
        const int ch = r * 256 + t;
        const int ss = ch >> 7;
        const int j = (ch >> 1) & 63;
        const int hh = ch & 1;
        bf16x8 v;
#pragma unroll
        for (int e = 0; e < 8; ++e)
            v[e] = (__bf16)s[(16 * ss + 8 * hh + e) * 65 + j];
        *(bf16x8*)(Atp + (size_t)o * 4096 + (size_t)ch * 8) = v;
    }
}

// ---------------------------------------------------------------------------
// main: block = 256 rows x 32 o's; 4 waves x 64 rows (2 row-tiles of 32).
// 3-buffer LDS pipeline, 2-deep prefetch via global_load_lds, raw s_barrier
// pairs with COUNTED vmcnt (stores issue every iter so the per-wave vmem
// ledger is uniform: 2 gld16 + 2 stores per iter -> wait vmcnt(8)).
// ---------------------------------------------------------------------------
__global__ __launch_bounds__(256, 2) void rbf_main(
    const float* __restrict__ x, const __bf16* __restrict__ Atp,
    const __bf16* __restrict__ cPhi, const __bf16* __restrict__ cPlo,
    const float* __restrict__ kArr, float* __restrict__ out)
{
    __shared__ __align__(16) __bf16 sA[3][4096];
    __shared__ __align__(16) float sLin[4][32][64];
    __shared__ float sK[32];

    const int tid = threadIdx.x;
    const int wave = tid >> 6;
    const int lane = tid & 63;
    const int b = lane & 31;
    const int h = lane >> 5;

    // 512 blocks = 8 XCD x (8 og x 8 bg); per-XCD 2MB Atp slice in its L2
    const int wg = (int)blockIdx.x;
    const int xcd = wg & 7;
    const int loc = wg >> 3;               // 0..63
    const int og = xcd * 8 + (loc >> 3);   // 0..63
    const int bg = loc & 7;                // 0..7
    const int oBase = og * 32;
    const int rowW = bg * 256 + wave * 64;

    const float* xr0 = x + (size_t)(rowW + b) * K_N;
    const float* xr1 = x + (size_t)(rowW + 32 + b) * K_N;

    const f32x16 zz = {0.f,0.f,0.f,0.f,0.f,0.f,0.f,0.f,
                       0.f,0.f,0.f,0.f,0.f,0.f,0.f,0.f};

    // x bf16 B-op frags (both tiles) + f32 dot copies
    bf16x8 xh[2][4];
    f32x4 xd[2][2][4];
    {
        bf16x8 xl[2][4];
#pragma unroll
        for (int t = 0; t < 2; ++t) {
            const float* xr = t ? xr1 : xr0;
#pragma unroll
            for (int ss = 0; ss < 4; ++ss) {
                const float* p = xr + ss * 16 + h * 8;
                bf16x8 vh, vl;
#pragma unroll
                for (int e = 0; e < 8; ++e) {
                    const float v = p[e];
                    const __bf16 hi = (__bf16)v;
                    vh[e] = hi;
                    vl[e] = (__bf16)(v - (float)hi);
                }
                xh[t][ss] = vh; xl[t][ss] = vl;
            }
#pragma unroll
            for (int mt = 0; mt < 2; ++mt)
#pragma unroll
                for (int rq = 0; rq < 4; ++rq)
                    xd[t][mt][rq] = *(const f32x4*)(xr + mt * 32 + rq * 8 + h * 4);
        }
        // linear-term GEMMs: lin[o][row] for 64 rows, scattered to sLin
        const __bf16* chp = cPhi + (size_t)og * 2048;
        const __bf16* clp = cPlo + (size_t)og * 2048;
        bf16x8 fh[4], fl[4];
#pragma unroll
        for (int ss = 0; ss < 4; ++ss) {
            fh[ss] = *(const bf16x8*)(chp + ss * 512 + b * 16 + h * 8);
            fl[ss] = *(const bf16x8*)(clp + ss * 512 + b * 16 + h * 8);
        }
#pragma unroll
        for (int t = 0; t < 2; ++t) {
            f32x16 lin = zz;
#pragma unroll
            for (int ss = 0; ss < 4; ++ss) {
                lin = __builtin_amdgcn_mfma_f32_32x32x16_bf16(fh[ss], xh[t][ss], lin, 0, 0, 0);
                lin = __builtin_amdgcn_mfma_f32_32x32x16_bf16(fh[ss], xl[t][ss], lin, 0, 0, 0);
                lin = __builtin_amdgcn_mfma_f32_32x32x16_bf16(fl[ss], xh[t][ss], lin, 0, 0, 0);
            }
#pragma unroll
            for (int r = 0; r < 16; ++r)
                sLin[wave][(r & 3) + 8 * (r >> 2) + 4 * h][t * 32 + b] = lin[r];
        }
    }
    if (tid < 32) sK[tid] = kArr[oBase + tid];
    __syncthreads();   // sLin/sK visible; vm/lgkm fully drained (clean ledger)

    // staging: linear LDS dest, pre-swizzled global src (involution swz)
    const int L0 = tid * 16, L1 = 4096 + tid * 16;
    const int S0 = L0 ^ (((L0 >> 7) & 7) << 4);
    const int S1 = L1 ^ (((L1 >> 7) & 7) << 4);
    const char* gp = (const char*)(Atp + (size_t)oBase * 4096);
    gld16(gp + S0, (char*)&sA[0][0] + L0);            // P0
    gld16(gp + S1, (char*)&sA[0][0] + L1);
    gld16(gp + 8192 + S0, (char*)&sA[1][0] + L0);     // P1
    gld16(gp + 8192 + S1, (char*)&sA[1][0] + L1);

    const int off0 = (b * 32 + h * 16) ^ (((b >> 2) & 7) << 4);
    float* o0 = out + (size_t)(rowW + b) * O_N + oBase;
    float* o1 = out + (size_t)(rowW + 32 + b) * O_N + oBase;

    auto body = [&](int i, const __bf16* bufp) {
        __builtin_amdgcn_s_setprio(1);
        f32x16 a00 = zz, a01 = zz, a10 = zz, a11 = zz;
#pragma unroll
        for (int ss = 0; ss < 4; ++ss) {
            const char* base = (const char*)bufp + ss * 2048;
            const bf16x8 f0 = *(const bf16x8*)(base + off0);
            const bf16x8 f1 = *(const bf16x8*)(base + 1024 + off0);
            a00 = __builtin_amdgcn_mfma_f32_32x32x16_bf16(f0, xh[0][ss], a00, 0, 0, 0);
            a10 = __builtin_amdgcn_mfma_f32_32x32x16_bf16(f0, xh[1][ss], a10, 0, 0, 0);
            a01 = __builtin_amdgcn_mfma_f32_32x32x16_bf16(f1, xh[0][ss], a01, 0, 0, 0);
            a11 = __builtin_amdgcn_mfma_f32_32x32x16_bf16(f1, xh[1][ss], a11, 0, 0, 0);
        }
        __builtin_amdgcn_s_setprio(0);
        const float kk = sK[i];
        {   // tile 0
            float p0 = 0.f, p1 = 0.f, p2 = 0.f, p3 = 0.f;
#pragma unroll
            for (int e = 0; e < 4; ++e) {
                p0 = fmaf(a00[e],      xd[0][0][0][e], p0);
                p1 = fmaf(a00[4 + e],  xd[0][0][1][e], p1);
                p2 = fmaf(a00[8 + e],  xd[0][0][2][e], p2);
                p3 = fmaf(a00[12 + e], xd[0][0][3][e], p3);
                p0 = fmaf(a01[e],      xd[0][1][0][e], p0);
                p1 = fmaf(a01[4 + e],  xd[0][1][1][e], p1);
                p2 = fmaf(a01[8 + e],  xd[0][1][2][e], p2);
                p3 = fmaf(a01[12 + e], xd[0][1][3][e], p3);
            }
            float q = (p0 + p1) + (p2 + p3);
            q += __shfl_xor(q, 32, 64);
            q += sLin[wave][i][b] + kk;
            const float ev = exp2f(q * -0.72134752044448170368f);
            if (h == 0) o0[i] = ev;
        }
        {   // tile 1
            float p0 = 0.f, p1 = 0.f, p2 = 0.f, p3 = 0.f;
#pragma unroll
            for (int e = 0; e < 4; ++e) {
                p0 = fmaf(a10[e],      xd[1][0][0][e], p0);
                p1 = fmaf(a10[4 + e],  xd[1][0][1][e], p1);
                p2 = fmaf(a10[8 + e],  xd[1][0][2][e], p2);
                p3 = fmaf(a10[12 + e], xd[1][0][3][e], p3);
                p0 = fmaf(a11[e],      xd[1][1][0][e], p0);
                p1 = fmaf(a11[4 + e],  xd[1][1][1][e], p1);
                p2 = fmaf(a11[8 + e],  xd[1][1][2][e], p2);
                p3 = fmaf(a11[12 + e], xd[1][1][3][e], p3);
            }
            float q = (p0 + p1) + (p2 + p3);
            q += __shfl_xor(q, 32, 64);
            q += sLin[wave][i][32 + b] + kk;
            const float ev = exp2f(q * -0.72134752044448170368f);
            if (h == 0) o1[i] = ev;
        }
    };

// per-iter vmem ledger (in-order retirement): 2 gld16 + 2 stores.
// At wait point of iter i, ops newer than P(i): stores(i-2,i-1) + P(i+1) +
// P(i+2) = 8 (i>=2); 4 at i=0; 6 at i=1.
#define RBF_ITER(I, BR, BW, WAIT) do {                                   \
    __builtin_amdgcn_s_barrier();          /* prev reads of buf BW done */\
    __builtin_amdgcn_sched_barrier(0);                                   \
    { const int pf_ = ((I) + 2 <= 31) ? ((I) + 2) : 31;                  \
      const char* gn_ = gp + (size_t)pf_ * 8192;                         \
      gld16(gn_ + S0, (char*)&sA[(BW)][0] + L0);                         \
      gld16(gn_ + S1, (char*)&sA[(BW)][0] + L1); }                       \
    asm volatile("s_waitcnt " WAIT ::: "memory");                        \
    __builtin_amdgcn_s_barrier();          /* buf BR ready for all */    \
    __builtin_amdgcn_sched_barrier(0);                                   \
    body((I), (const __bf16*)&sA[(BR)][0]);                              \
} while (0)

    RBF_ITER(0, 0, 2, "vmcnt(4)");
    RBF_ITER(1, 1, 0, "vmcnt(6)");
#pragma unroll 1
    for (int ii = 0; ii < 10; ++ii) {
        const int i = 2 + ii * 3;
        RBF_ITER(i,     2, 1, "vmcnt(8)");
        RBF_ITER(i + 1, 0, 2, "vmcnt(8)");
        RBF_ITER(i + 2, 1, 0, "vmcnt(8)");
    }
#undef RBF_ITER
}

extern "C" void kernel_launch(void* const* d_in, const int* in_sizes, int n_in,
                              void* d_out, int out_size, void* d_ws, size_t ws_size,
                              hipStream_t stream)
{
    const float* x = (const float*)d_in[0];
    const float* means = (const float*)d_in[1];
    const float* inv = (const float*)d_in[2];
    float* out = (float*)d_out;

    char* w = (char*)d_ws;
    __bf16* Atp  = (__bf16*)w;                                     // 16.78 MB
    __bf16* cPhi = (__bf16*)(w + (size_t)O_N * 4096 * 2);          // 256 KB
    __bf16* cPlo = (__bf16*)(w + (size_t)O_N * 4096 * 2 + 262144); // 256 KB
    float*  kArr = (float*)(w + (size_t)O_N * 4096 * 2 + 524288);  // 8 KB

    rbf_prep<<<dim3(O_N), dim3(256), 0, stream>>>(inv, means, Atp, cPhi, cPlo, kArr);
    rbf_main<<<dim3(512), dim3(256), 0, stream>>>(x, Atp, cPhi, cPlo, kArr, out);

    (void)in_sizes; (void)n_in; (void)out_size; (void)ws_size;
}